// Round 1
// baseline (1763.759 us; speedup 1.0000x reference)
//
#include <hip/hip_runtime.h>

#define NNODES 50000
#define NEDGES 200000
#define DDIM 512

// ---------------------------------------------------------------------------
// GEMM: C[M,512] = A[M,512] @ B[512,512] + bias   (fp32, LDS-tiled 64x64)
// ---------------------------------------------------------------------------
__global__ __launch_bounds__(256) void gemm_bias_kernel(
    const float* __restrict__ A, const float* __restrict__ B,
    const float* __restrict__ bias, float* __restrict__ C, int M) {
  const int K = DDIM, N = DDIM;
  __shared__ float As[16][64 + 1];   // As[k][m]
  __shared__ float Bs[16][64 + 4];   // Bs[k][n]
  const int tid = threadIdx.x;
  const int bm = blockIdx.y * 64;
  const int bn = blockIdx.x * 64;
  const int tx = tid & 15, ty = tid >> 4;

  float acc[4][4] = {};

  const int ar = tid >> 2;           // 0..63  (A row within tile)
  const int ac = (tid & 3) * 4;      // 0,4,8,12 (A col group within k-tile)
  const int br = tid >> 4;           // 0..15  (B row within k-tile)
  const int bc = (tid & 15) * 4;     // 0..60  (B col group)

  for (int k0 = 0; k0 < K; k0 += 16) {
    float4 av;
    if (bm + ar < M)
      av = *(const float4*)&A[(size_t)(bm + ar) * K + k0 + ac];
    else
      av = make_float4(0.f, 0.f, 0.f, 0.f);
    As[ac + 0][ar] = av.x;
    As[ac + 1][ar] = av.y;
    As[ac + 2][ar] = av.z;
    As[ac + 3][ar] = av.w;

    float4 bv = *(const float4*)&B[(size_t)(k0 + br) * N + bn + bc];
    Bs[br][bc + 0] = bv.x;
    Bs[br][bc + 1] = bv.y;
    Bs[br][bc + 2] = bv.z;
    Bs[br][bc + 3] = bv.w;

    __syncthreads();

#pragma unroll
    for (int k = 0; k < 16; ++k) {
      float a[4], bb[4];
#pragma unroll
      for (int i = 0; i < 4; ++i) a[i] = As[k][ty * 4 + i];
#pragma unroll
      for (int j = 0; j < 4; ++j) bb[j] = Bs[k][tx * 4 + j];
#pragma unroll
      for (int i = 0; i < 4; ++i)
#pragma unroll
        for (int j = 0; j < 4; ++j) acc[i][j] += a[i] * bb[j];
    }
    __syncthreads();
  }

#pragma unroll
  for (int i = 0; i < 4; ++i) {
    const int row = bm + ty * 4 + i;
    if (row < M) {
#pragma unroll
      for (int j = 0; j < 4; ++j) {
        C[(size_t)row * N + bn + tx * 4 + j] = acc[i][j] + bias[bn + tx * 4 + j];
      }
    }
  }
}

// ---------------------------------------------------------------------------
// Scatter: for each edge e: sums[dst[e]] += h_proj[src[e]] * ew[e]; cnt[dst]++
// 128 threads per edge (each thread handles one float4 = 4 of 512 floats).
// ---------------------------------------------------------------------------
__global__ __launch_bounds__(256) void scatter_kernel(
    const float* __restrict__ hp, const float* __restrict__ ew,
    const int* __restrict__ src, const int* __restrict__ dst,
    float* __restrict__ sums, float* __restrict__ cnt, int E) {
  const int e = blockIdx.x * 2 + (threadIdx.x >> 7);
  if (e >= E) return;
  const int lane = threadIdx.x & 127;
  const int s = src[e];
  const int d = dst[e];
  const float w = ew[e];
  const float4 v = ((const float4*)&hp[(size_t)s * DDIM])[lane];
  float* orow = &sums[(size_t)d * DDIM];
  atomicAdd(&orow[lane * 4 + 0], v.x * w);
  atomicAdd(&orow[lane * 4 + 1], v.y * w);
  atomicAdd(&orow[lane * 4 + 2], v.z * w);
  atomicAdd(&orow[lane * 4 + 3], v.w * w);
  if (lane == 0) atomicAdd(&cnt[d], 1.0f);
}

// ---------------------------------------------------------------------------
// Finalize: out = relu(out / max(cnt,1))
// ---------------------------------------------------------------------------
__global__ __launch_bounds__(256) void finalize_kernel(
    float* __restrict__ out, const float* __restrict__ cnt, int total) {
  for (int i = blockIdx.x * blockDim.x + threadIdx.x; i < total;
       i += gridDim.x * blockDim.x) {
    const float c = cnt[i >> 9];  // i / 512
    const float v = out[i];
    out[i] = fmaxf(v / fmaxf(c, 1.0f), 0.0f);
  }
}

extern "C" void kernel_launch(void* const* d_in, const int* in_sizes, int n_in,
                              void* d_out, int out_size, void* d_ws, size_t ws_size,
                              hipStream_t stream) {
  const float* h  = (const float*)d_in[0];   // [50000,512]
  const float* W  = (const float*)d_in[1];   // [512,512]
  const float* b  = (const float*)d_in[2];   // [512]
  const float* ew = (const float*)d_in[3];   // [200000]
  const int* src  = (const int*)d_in[4];     // [200000]
  const int* dst  = (const int*)d_in[5];     // [200000]
  float* out = (float*)d_out;                // [50000,512] — used as sums acc

  // Workspace layout: h_proj [50000*512] fp32, then cnt [50000] fp32
  float* h_proj = (float*)d_ws;
  float* cnt = (float*)((char*)d_ws + (size_t)NNODES * DDIM * sizeof(float));

  // 1) GEMM: h_proj = h @ W + b
  dim3 ggrid(DDIM / 64, (NNODES + 63) / 64);
  gemm_bias_kernel<<<ggrid, 256, 0, stream>>>(h, W, b, h_proj, NNODES);

  // 2) zero accumulators
  hipMemsetAsync(out, 0, (size_t)out_size * sizeof(float), stream);
  hipMemsetAsync(cnt, 0, (size_t)NNODES * sizeof(float), stream);

  // 3) scatter-add messages
  scatter_kernel<<<(NEDGES + 1) / 2, 256, 0, stream>>>(h_proj, ew, src, dst,
                                                       out, cnt, NEDGES);

  // 4) finalize: mean + relu
  finalize_kernel<<<2048, 256, 0, stream>>>(out, cnt, NNODES * DDIM);
}

// Round 2
// 492.866 us; speedup vs baseline: 3.5786x; 3.5786x over previous
//
#include <hip/hip_runtime.h>

#define NNODES 50000
#define NEDGES 200000
#define DDIM 512

static __device__ __forceinline__ unsigned short f2bf(float f) {
  unsigned u = __float_as_uint(f);
  unsigned r = (u + 0x7fffu + ((u >> 16) & 1u)) >> 16;  // RNE
  return (unsigned short)r;
}

// ---------------------------------------------------------------------------
// GEMM: C[M,512] = bf16( A[M,512] @ B[512,512] + bias )  (fp32 math, bf16 out)
// ---------------------------------------------------------------------------
__global__ __launch_bounds__(256) void gemm_bias_kernel(
    const float* __restrict__ A, const float* __restrict__ B,
    const float* __restrict__ bias, unsigned short* __restrict__ C, int M) {
  const int K = DDIM, N = DDIM;
  __shared__ float As[16][64 + 1];   // As[k][m]
  __shared__ float Bs[16][64 + 4];   // Bs[k][n]
  const int tid = threadIdx.x;
  const int bm = blockIdx.y * 64;
  const int bn = blockIdx.x * 64;
  const int tx = tid & 15, ty = tid >> 4;

  float acc[4][4] = {};

  const int ar = tid >> 2;           // 0..63
  const int ac = (tid & 3) * 4;      // 0,4,8,12
  const int br = tid >> 4;           // 0..15
  const int bc = (tid & 15) * 4;     // 0..60

  for (int k0 = 0; k0 < K; k0 += 16) {
    float4 av;
    if (bm + ar < M)
      av = *(const float4*)&A[(size_t)(bm + ar) * K + k0 + ac];
    else
      av = make_float4(0.f, 0.f, 0.f, 0.f);
    As[ac + 0][ar] = av.x;
    As[ac + 1][ar] = av.y;
    As[ac + 2][ar] = av.z;
    As[ac + 3][ar] = av.w;

    float4 bv = *(const float4*)&B[(size_t)(k0 + br) * N + bn + bc];
    Bs[br][bc + 0] = bv.x;
    Bs[br][bc + 1] = bv.y;
    Bs[br][bc + 2] = bv.z;
    Bs[br][bc + 3] = bv.w;

    __syncthreads();

#pragma unroll
    for (int k = 0; k < 16; ++k) {
      float a[4], bb[4];
#pragma unroll
      for (int i = 0; i < 4; ++i) a[i] = As[k][ty * 4 + i];
#pragma unroll
      for (int j = 0; j < 4; ++j) bb[j] = Bs[k][tx * 4 + j];
#pragma unroll
      for (int i = 0; i < 4; ++i)
#pragma unroll
        for (int j = 0; j < 4; ++j) acc[i][j] += a[i] * bb[j];
    }
    __syncthreads();
  }

#pragma unroll
  for (int i = 0; i < 4; ++i) {
    const int row = bm + ty * 4 + i;
    if (row < M) {
      ushort4 pk;
      pk.x = f2bf(acc[i][0] + bias[bn + tx * 4 + 0]);
      pk.y = f2bf(acc[i][1] + bias[bn + tx * 4 + 1]);
      pk.z = f2bf(acc[i][2] + bias[bn + tx * 4 + 2]);
      pk.w = f2bf(acc[i][3] + bias[bn + tx * 4 + 3]);
      *(ushort4*)&C[(size_t)row * N + bn + tx * 4] = pk;
    }
  }
}

// ---------------------------------------------------------------------------
// CSR build: histogram of dst
// ---------------------------------------------------------------------------
__global__ __launch_bounds__(256) void hist_kernel(const int* __restrict__ dst,
                                                   int* __restrict__ deg, int E) {
  const int e = blockIdx.x * 256 + threadIdx.x;
  if (e < E) atomicAdd(&deg[dst[e]], 1);
}

// ---------------------------------------------------------------------------
// Exclusive prefix scan over deg[0..n) -> off[0..n], single 1024-thread block.
// Wave-level shfl scan + 16-wave LDS combine; running total across chunks.
// ---------------------------------------------------------------------------
__global__ __launch_bounds__(1024) void scan_kernel(const int* __restrict__ deg,
                                                    int* __restrict__ off, int n) {
  __shared__ int wsum[16];
  __shared__ int s_running;
  const int tid = threadIdx.x;
  const int lane = tid & 63, wid = tid >> 6;
  if (tid == 0) { s_running = 0; off[0] = 0; }
  __syncthreads();
  for (int base = 0; base < n; base += 1024) {
    const int i = base + tid;
    int v = (i < n) ? deg[i] : 0;
    int incl = v;
#pragma unroll
    for (int s = 1; s < 64; s <<= 1) {
      int t = __shfl_up(incl, s, 64);
      if (lane >= s) incl += t;
    }
    if (lane == 63) wsum[wid] = incl;
    __syncthreads();
    if (wid == 0 && lane < 16) {
      int wv = wsum[lane];
#pragma unroll
      for (int s = 1; s < 16; s <<= 1) {
        int t = __shfl_up(wv, s, 16);
        if (lane >= s) wv += t;
      }
      wsum[lane] = wv;
    }
    __syncthreads();
    const int waveoff = (wid > 0) ? wsum[wid - 1] : 0;
    const int run = s_running;
    incl += waveoff;                       // block-inclusive scan value
    if (i < n) off[i + 1] = run + incl;
    __syncthreads();
    if (tid == 1023) s_running = run + incl;  // block total (OOB lanes add 0)
    __syncthreads();
  }
}

__global__ __launch_bounds__(256) void copy_kernel(const int* __restrict__ off,
                                                   int* __restrict__ cur, int n) {
  const int i = blockIdx.x * 256 + threadIdx.x;
  if (i < n) cur[i] = off[i];
}

// ---------------------------------------------------------------------------
// CSR fill: slot per edge via per-dst cursor; store src index and weight.
// ---------------------------------------------------------------------------
__global__ __launch_bounds__(256) void fill_kernel(
    const int* __restrict__ src, const int* __restrict__ dst,
    const float* __restrict__ ew, int* __restrict__ cur,
    int* __restrict__ esrc, float* __restrict__ ews, int E) {
  const int e = blockIdx.x * 256 + threadIdx.x;
  if (e >= E) return;
  const int p = atomicAdd(&cur[dst[e]], 1);
  esrc[p] = src[e];
  ews[p] = ew[e];
}

// ---------------------------------------------------------------------------
// Gather: one wave per node; sum w * h_proj_bf16[src] over CSR range, then
// mean + relu, write fp32 output row once. No atomics.
// ---------------------------------------------------------------------------
__global__ __launch_bounds__(256) void gather_kernel(
    const unsigned short* __restrict__ hp, const int* __restrict__ off,
    const int* __restrict__ esrc, const float* __restrict__ ews,
    float* __restrict__ out, int n) {
  const int node = blockIdx.x * 4 + (threadIdx.x >> 6);
  if (node >= n) return;
  const int lane = threadIdx.x & 63;
  const int beg = off[node], end = off[node + 1];

  float acc[8] = {0.f, 0.f, 0.f, 0.f, 0.f, 0.f, 0.f, 0.f};
  for (int p = beg; p < end; ++p) {
    const int s = esrc[p];
    const float w = ews[p];
    const uint4 u = *(const uint4*)(hp + (size_t)s * DDIM + lane * 8);
    const unsigned uu[4] = {u.x, u.y, u.z, u.w};
#pragma unroll
    for (int q = 0; q < 4; ++q) {
      const float lo = __uint_as_float(uu[q] << 16);
      const float hi = __uint_as_float(uu[q] & 0xffff0000u);
      acc[2 * q + 0] += w * lo;
      acc[2 * q + 1] += w * hi;
    }
  }

  const float inv = 1.0f / fmaxf((float)(end - beg), 1.0f);
  float4 o0, o1;
  o0.x = fmaxf(acc[0] * inv, 0.f);
  o0.y = fmaxf(acc[1] * inv, 0.f);
  o0.z = fmaxf(acc[2] * inv, 0.f);
  o0.w = fmaxf(acc[3] * inv, 0.f);
  o1.x = fmaxf(acc[4] * inv, 0.f);
  o1.y = fmaxf(acc[5] * inv, 0.f);
  o1.z = fmaxf(acc[6] * inv, 0.f);
  o1.w = fmaxf(acc[7] * inv, 0.f);
  float* orow = out + (size_t)node * DDIM + lane * 8;
  *(float4*)(orow + 0) = o0;
  *(float4*)(orow + 4) = o1;
}

extern "C" void kernel_launch(void* const* d_in, const int* in_sizes, int n_in,
                              void* d_out, int out_size, void* d_ws, size_t ws_size,
                              hipStream_t stream) {
  const float* h  = (const float*)d_in[0];   // [50000,512]
  const float* W  = (const float*)d_in[1];   // [512,512]
  const float* b  = (const float*)d_in[2];   // [512]
  const float* ew = (const float*)d_in[3];   // [200000]
  const int* src  = (const int*)d_in[4];     // [200000]
  const int* dst  = (const int*)d_in[5];     // [200000]
  float* out = (float*)d_out;                // [50000,512]

  // Workspace layout (256B-aligned chunks)
  char* ws = (char*)d_ws;
  size_t o = 0;
  auto alloc = [&](size_t bytes) {
    char* p = ws + o;
    o += (bytes + 255) & ~(size_t)255;
    return p;
  };
  unsigned short* hp = (unsigned short*)alloc((size_t)NNODES * DDIM * 2);  // 51.2 MB
  int* deg   = (int*)alloc((size_t)NNODES * 4);
  int* off   = (int*)alloc((size_t)(NNODES + 1) * 4);
  int* cur   = (int*)alloc((size_t)NNODES * 4);
  int* esrc  = (int*)alloc((size_t)NEDGES * 4);
  float* ews = (float*)alloc((size_t)NEDGES * 4);

  // 1) GEMM: hp = bf16(h @ W + b)
  dim3 ggrid(DDIM / 64, (NNODES + 63) / 64);
  gemm_bias_kernel<<<ggrid, 256, 0, stream>>>(h, W, b, hp, NNODES);

  // 2) CSR build by dst
  hipMemsetAsync(deg, 0, (size_t)NNODES * 4, stream);
  hist_kernel<<<(NEDGES + 255) / 256, 256, 0, stream>>>(dst, deg, NEDGES);
  scan_kernel<<<1, 1024, 0, stream>>>(deg, off, NNODES);
  copy_kernel<<<(NNODES + 255) / 256, 256, 0, stream>>>(off, cur, NNODES);
  fill_kernel<<<(NEDGES + 255) / 256, 256, 0, stream>>>(src, dst, ew, cur,
                                                        esrc, ews, NEDGES);

  // 3) Gather + mean + relu (one wave per node, no atomics)
  gather_kernel<<<(NNODES + 3) / 4, 256, 0, stream>>>(hp, off, esrc, ews, out,
                                                      NNODES);
}

// Round 3
// 222.140 us; speedup vs baseline: 7.9398x; 2.2187x over previous
//
#include <hip/hip_runtime.h>

#define NNODES 50000
#define NEDGES 200000
#define DDIM 512

typedef __attribute__((ext_vector_type(8))) short bf16x8;
typedef __attribute__((ext_vector_type(4))) float f32x4;

static __device__ __forceinline__ unsigned short f2bf(float f) {
  unsigned u = __float_as_uint(f);
  unsigned r = (u + 0x7fffu + ((u >> 16) & 1u)) >> 16;  // RNE
  return (unsigned short)r;
}

static __device__ __forceinline__ void gload_lds16(const void* g, void* l) {
  __builtin_amdgcn_global_load_lds(
      (const __attribute__((address_space(1))) unsigned int*)g,
      (__attribute__((address_space(3))) unsigned int*)l, 16, 0, 0);
}

// ---------------------------------------------------------------------------
// Convert h (fp32) -> bf16, 8 elements/thread
// ---------------------------------------------------------------------------
__global__ __launch_bounds__(256) void cvt_h_kernel(
    const float* __restrict__ in, unsigned short* __restrict__ out, int n8) {
  for (int i = blockIdx.x * 256 + threadIdx.x; i < n8; i += gridDim.x * 256) {
    const float4 v0 = ((const float4*)in)[(size_t)i * 2];
    const float4 v1 = ((const float4*)in)[(size_t)i * 2 + 1];
    uint4 p;
    p.x = (unsigned)f2bf(v0.x) | ((unsigned)f2bf(v0.y) << 16);
    p.y = (unsigned)f2bf(v0.z) | ((unsigned)f2bf(v0.w) << 16);
    p.z = (unsigned)f2bf(v1.x) | ((unsigned)f2bf(v1.y) << 16);
    p.w = (unsigned)f2bf(v1.z) | ((unsigned)f2bf(v1.w) << 16);
    ((uint4*)out)[i] = p;
  }
}

// ---------------------------------------------------------------------------
// Wt[n][k] = bf16(W[k][n])  (512x512 transpose via LDS)
// ---------------------------------------------------------------------------
__global__ __launch_bounds__(256) void cvt_wt_kernel(
    const float* __restrict__ W, unsigned short* __restrict__ Wt) {
  __shared__ float t[32][33];
  const int n0 = blockIdx.x * 32, k0 = blockIdx.y * 32;
  const int tx = threadIdx.x & 31, ty = threadIdx.x >> 5;  // ty 0..7
  for (int r = ty; r < 32; r += 8)
    t[r][tx] = W[(size_t)(k0 + r) * DDIM + n0 + tx];
  __syncthreads();
  for (int r = ty; r < 32; r += 8)
    Wt[(size_t)(n0 + r) * DDIM + k0 + tx] = f2bf(t[tx][r]);
}

// ---------------------------------------------------------------------------
// MFMA GEMM: C_bf16[M,512] = A_bf16[M,512] @ Wt_bf16[512,512]^T + bias
// 128x128 tile, BK=32, 4 waves (2x2), 16x16x32 MFMA, global_load_lds staging.
// ---------------------------------------------------------------------------
__global__ __launch_bounds__(256) void gemm_mfma_kernel(
    const unsigned short* __restrict__ Ab, const unsigned short* __restrict__ Bt,
    const float* __restrict__ bias, unsigned short* __restrict__ C, int M) {
  __shared__ unsigned short As[128 * 32];
  __shared__ unsigned short Bs[128 * 32];
  const int tid = threadIdx.x;
  const int wid = tid >> 6, lane = tid & 63;
  const int mt = blockIdx.x >> 2, nt = blockIdx.x & 3;
  const int bm = mt * 128, bn = nt * 128;
  const int wr = wid >> 1, wc = wid & 1;

  f32x4 acc[4][4] = {};

  // staging: linear index ln = it*256 + tid; row = ln>>2, colgrp = ln&3
  const int r0 = tid >> 2, cg = tid & 3;
  const int arow0 = min(bm + r0, M - 1);
  const int arow1 = min(bm + r0 + 64, M - 1);

  const unsigned short* a0 = Ab + (size_t)arow0 * DDIM + cg * 8;
  const unsigned short* a1 = Ab + (size_t)arow1 * DDIM + cg * 8;
  const unsigned short* b0 = Bt + (size_t)(bn + r0) * DDIM + cg * 8;
  const unsigned short* b1 = Bt + (size_t)(bn + r0 + 64) * DDIM + cg * 8;

  unsigned short* lA0 = As + (wid * 64) * 8;        // wave-uniform bases
  unsigned short* lA1 = As + (256 + wid * 64) * 8;
  unsigned short* lB0 = Bs + (wid * 64) * 8;
  unsigned short* lB1 = Bs + (256 + wid * 64) * 8;

  const int l16 = lane & 15, lk = lane >> 4;

  for (int k0 = 0; k0 < DDIM; k0 += 32) {
    gload_lds16(a0 + k0, lA0);
    gload_lds16(a1 + k0, lA1);
    gload_lds16(b0 + k0, lB0);
    gload_lds16(b1 + k0, lB1);
    __syncthreads();

    bf16x8 af[4], bfr[4];
#pragma unroll
    for (int i = 0; i < 4; ++i) {
      af[i]  = *(const bf16x8*)&As[(wr * 64 + i * 16 + l16) * 32 + lk * 8];
      bfr[i] = *(const bf16x8*)&Bs[(wc * 64 + i * 16 + l16) * 32 + lk * 8];
    }
#pragma unroll
    for (int i = 0; i < 4; ++i)
#pragma unroll
      for (int j = 0; j < 4; ++j)
        acc[i][j] = __builtin_amdgcn_mfma_f32_16x16x32_bf16(af[i], bfr[j],
                                                            acc[i][j], 0, 0, 0);
    __syncthreads();
  }

  // Epilogue: C[row][col], col = lane&15 (+j*16), row = (lane>>4)*4+q (+i*16)
#pragma unroll
  for (int j = 0; j < 4; ++j) {
    const int col = bn + wc * 64 + j * 16 + l16;
    const float bv = bias[col];
#pragma unroll
    for (int i = 0; i < 4; ++i) {
      const int rbase = bm + wr * 64 + i * 16 + lk * 4;
#pragma unroll
      for (int q = 0; q < 4; ++q) {
        const int row = rbase + q;
        if (row < M) C[(size_t)row * DDIM + col] = f2bf(acc[i][j][q] + bv);
      }
    }
  }
}

// ---------------------------------------------------------------------------
// CSR build: histogram of dst
// ---------------------------------------------------------------------------
__global__ __launch_bounds__(256) void hist_kernel(const int* __restrict__ dst,
                                                   int* __restrict__ deg, int E) {
  const int e = blockIdx.x * 256 + threadIdx.x;
  if (e < E) atomicAdd(&deg[dst[e]], 1);
}

// ---------------------------------------------------------------------------
// Exclusive prefix scan over deg[0..n) -> off[0..n], single 1024-thread block.
// ---------------------------------------------------------------------------
__global__ __launch_bounds__(1024) void scan_kernel(const int* __restrict__ deg,
                                                    int* __restrict__ off, int n) {
  __shared__ int wsum[16];
  __shared__ int s_running;
  const int tid = threadIdx.x;
  const int lane = tid & 63, wid = tid >> 6;
  if (tid == 0) { s_running = 0; off[0] = 0; }
  __syncthreads();
  for (int base = 0; base < n; base += 1024) {
    const int i = base + tid;
    int v = (i < n) ? deg[i] : 0;
    int incl = v;
#pragma unroll
    for (int s = 1; s < 64; s <<= 1) {
      int t = __shfl_up(incl, s, 64);
      if (lane >= s) incl += t;
    }
    if (lane == 63) wsum[wid] = incl;
    __syncthreads();
    if (wid == 0 && lane < 16) {
      int wv = wsum[lane];
#pragma unroll
      for (int s = 1; s < 16; s <<= 1) {
        int t = __shfl_up(wv, s, 16);
        if (lane >= s) wv += t;
      }
      wsum[lane] = wv;
    }
    __syncthreads();
    const int waveoff = (wid > 0) ? wsum[wid - 1] : 0;
    const int run = s_running;
    incl += waveoff;
    if (i < n) off[i + 1] = run + incl;
    __syncthreads();
    if (tid == 1023) s_running = run + incl;
    __syncthreads();
  }
}

__global__ __launch_bounds__(256) void copy_kernel(const int* __restrict__ off,
                                                   int* __restrict__ cur, int n) {
  const int i = blockIdx.x * 256 + threadIdx.x;
  if (i < n) cur[i] = off[i];
}

__global__ __launch_bounds__(256) void fill_kernel(
    const int* __restrict__ src, const int* __restrict__ dst,
    const float* __restrict__ ew, int* __restrict__ cur,
    int* __restrict__ esrc, float* __restrict__ ews, int E) {
  const int e = blockIdx.x * 256 + threadIdx.x;
  if (e >= E) return;
  const int p = atomicAdd(&cur[dst[e]], 1);
  esrc[p] = src[e];
  ews[p] = ew[e];
}

// ---------------------------------------------------------------------------
// Gather: one wave per node; mean + relu, single fp32 row write. No atomics.
// ---------------------------------------------------------------------------
__global__ __launch_bounds__(256) void gather_kernel(
    const unsigned short* __restrict__ hp, const int* __restrict__ off,
    const int* __restrict__ esrc, const float* __restrict__ ews,
    float* __restrict__ out, int n) {
  const int node = blockIdx.x * 4 + (threadIdx.x >> 6);
  if (node >= n) return;
  const int lane = threadIdx.x & 63;
  const int beg = off[node], end = off[node + 1];

  float acc[8] = {0.f, 0.f, 0.f, 0.f, 0.f, 0.f, 0.f, 0.f};
  for (int p = beg; p < end; ++p) {
    const int s = esrc[p];
    const float w = ews[p];
    const uint4 u = *(const uint4*)(hp + (size_t)s * DDIM + lane * 8);
    const unsigned uu[4] = {u.x, u.y, u.z, u.w};
#pragma unroll
    for (int q = 0; q < 4; ++q) {
      const float lo = __uint_as_float(uu[q] << 16);
      const float hi = __uint_as_float(uu[q] & 0xffff0000u);
      acc[2 * q + 0] += w * lo;
      acc[2 * q + 1] += w * hi;
    }
  }

  const float inv = 1.0f / fmaxf((float)(end - beg), 1.0f);
  float4 o0, o1;
  o0.x = fmaxf(acc[0] * inv, 0.f);
  o0.y = fmaxf(acc[1] * inv, 0.f);
  o0.z = fmaxf(acc[2] * inv, 0.f);
  o0.w = fmaxf(acc[3] * inv, 0.f);
  o1.x = fmaxf(acc[4] * inv, 0.f);
  o1.y = fmaxf(acc[5] * inv, 0.f);
  o1.z = fmaxf(acc[6] * inv, 0.f);
  o1.w = fmaxf(acc[7] * inv, 0.f);
  float* orow = out + (size_t)node * DDIM + lane * 8;
  *(float4*)(orow + 0) = o0;
  *(float4*)(orow + 4) = o1;
}

extern "C" void kernel_launch(void* const* d_in, const int* in_sizes, int n_in,
                              void* d_out, int out_size, void* d_ws, size_t ws_size,
                              hipStream_t stream) {
  const float* h  = (const float*)d_in[0];
  const float* W  = (const float*)d_in[1];
  const float* b  = (const float*)d_in[2];
  const float* ew = (const float*)d_in[3];
  const int* src  = (const int*)d_in[4];
  const int* dst  = (const int*)d_in[5];
  float* out = (float*)d_out;

  // bf16 h and Wt live in d_out (dead before gather overwrites d_out fully)
  unsigned short* hb = (unsigned short*)d_out;                    // 51.2 MB
  unsigned short* Wt = (unsigned short*)((char*)d_out + (size_t)NNODES * DDIM * 2);  // 0.5 MB

  // Workspace: hp (bf16 h_proj) + CSR arrays
  char* ws = (char*)d_ws;
  size_t o = 0;
  auto alloc = [&](size_t bytes) {
    char* p = ws + o;
    o += (bytes + 255) & ~(size_t)255;
    return p;
  };
  unsigned short* hp = (unsigned short*)alloc((size_t)NNODES * DDIM * 2);  // 51.2 MB
  int* deg   = (int*)alloc((size_t)NNODES * 4);
  int* off   = (int*)alloc((size_t)(NNODES + 1) * 4);
  int* cur   = (int*)alloc((size_t)NNODES * 4);
  int* esrc  = (int*)alloc((size_t)NEDGES * 4);
  float* ews = (float*)alloc((size_t)NEDGES * 4);

  // 1) fp32 -> bf16 conversions
  cvt_h_kernel<<<2048, 256, 0, stream>>>(h, hb, NNODES * DDIM / 8);
  dim3 wgrid(16, 16);
  cvt_wt_kernel<<<wgrid, 256, 0, stream>>>(W, Wt);

  // 2) MFMA GEMM: hp = bf16(hb @ Wt^T + b)
  const int mtiles = (NNODES + 127) / 128;  // 391
  gemm_mfma_kernel<<<mtiles * 4, 256, 0, stream>>>(hb, Wt, b, hp, NNODES);

  // 3) CSR build by dst
  hipMemsetAsync(deg, 0, (size_t)NNODES * 4, stream);
  hist_kernel<<<(NEDGES + 255) / 256, 256, 0, stream>>>(dst, deg, NEDGES);
  scan_kernel<<<1, 1024, 0, stream>>>(deg, off, NNODES);
  copy_kernel<<<(NNODES + 255) / 256, 256, 0, stream>>>(off, cur, NNODES);
  fill_kernel<<<(NEDGES + 255) / 256, 256, 0, stream>>>(src, dst, ew, cur,
                                                        esrc, ews, NEDGES);

  // 4) Gather + mean + relu (one wave per node)
  gather_kernel<<<(NNODES + 3) / 4, 256, 0, stream>>>(hp, off, esrc, ews, out,
                                                      NNODES);
}

// Round 4
// 213.531 us; speedup vs baseline: 8.2600x; 1.0403x over previous
//
#include <hip/hip_runtime.h>

#define NNODES 50000
#define NEDGES 200000
#define DDIM 512

typedef __attribute__((ext_vector_type(8))) short bf16x8;
typedef __attribute__((ext_vector_type(4))) float f32x4;

static __device__ __forceinline__ unsigned short f2bf(float f) {
  unsigned u = __float_as_uint(f);
  unsigned r = (u + 0x7fffu + ((u >> 16) & 1u)) >> 16;  // RNE
  return (unsigned short)r;
}

static __device__ __forceinline__ void gload_lds16(const void* g, void* l) {
  __builtin_amdgcn_global_load_lds(
      (const __attribute__((address_space(1))) unsigned int*)g,
      (__attribute__((address_space(3))) unsigned int*)l, 16, 0, 0);
}

// ---------------------------------------------------------------------------
// Convert h (fp32) -> bf16, 8 elements/thread
// ---------------------------------------------------------------------------
__global__ __launch_bounds__(256) void cvt_h_kernel(
    const float* __restrict__ in, unsigned short* __restrict__ out, int n8) {
  for (int i = blockIdx.x * 256 + threadIdx.x; i < n8; i += gridDim.x * 256) {
    const float4 v0 = ((const float4*)in)[(size_t)i * 2];
    const float4 v1 = ((const float4*)in)[(size_t)i * 2 + 1];
    uint4 p;
    p.x = (unsigned)f2bf(v0.x) | ((unsigned)f2bf(v0.y) << 16);
    p.y = (unsigned)f2bf(v0.z) | ((unsigned)f2bf(v0.w) << 16);
    p.z = (unsigned)f2bf(v1.x) | ((unsigned)f2bf(v1.y) << 16);
    p.w = (unsigned)f2bf(v1.z) | ((unsigned)f2bf(v1.w) << 16);
    ((uint4*)out)[i] = p;
  }
}

// ---------------------------------------------------------------------------
// Wt[n][k] = bf16(W[k][n])  (512x512 transpose via LDS)
// ---------------------------------------------------------------------------
__global__ __launch_bounds__(256) void cvt_wt_kernel(
    const float* __restrict__ W, unsigned short* __restrict__ Wt) {
  __shared__ float t[32][33];
  const int n0 = blockIdx.x * 32, k0 = blockIdx.y * 32;
  const int tx = threadIdx.x & 31, ty = threadIdx.x >> 5;  // ty 0..7
  for (int r = ty; r < 32; r += 8)
    t[r][tx] = W[(size_t)(k0 + r) * DDIM + n0 + tx];
  __syncthreads();
  for (int r = ty; r < 32; r += 8)
    Wt[(size_t)(n0 + r) * DDIM + k0 + tx] = f2bf(t[tx][r]);
}

// ---------------------------------------------------------------------------
// MFMA GEMM: C_bf16[M,512] = A_bf16[M,512] @ Wt_bf16[512,512]^T + bias
// 128x128 tile, BK=32, 4 waves (2x2), 16x16x32 MFMA, global_load_lds staging.
// LDS XOR swizzle (both-sides): source cg ^= (row>>1)&3, read lk ^= (l16>>1)&3.
// XCD-chunked bijective blockIdx swizzle for A-tile L2 reuse.
// ---------------------------------------------------------------------------
__global__ __launch_bounds__(256) void gemm_mfma_kernel(
    const unsigned short* __restrict__ Ab, const unsigned short* __restrict__ Bt,
    const float* __restrict__ bias, unsigned short* __restrict__ C, int M) {
  __shared__ unsigned short As[128 * 32];
  __shared__ unsigned short Bs[128 * 32];
  const int tid = threadIdx.x;
  const int wid = tid >> 6, lane = tid & 63;

  // bijective XCD-chunked remap (8 XCDs)
  const int nwg = gridDim.x;
  const int q = nwg >> 3, rr = nwg & 7;
  const int x = blockIdx.x & 7, idx = blockIdx.x >> 3;
  const int wg = x * q + min(x, rr) + idx;

  const int mt = wg >> 2, nt = wg & 3;
  const int bm = mt * 128, bn = nt * 128;
  const int wr = wid >> 1, wc = wid & 1;

  f32x4 acc[4][4] = {};

  // staging: slot s0 = wid*64+lane (first half), +256 second half.
  // LDS dest stays linear; swizzle applied to the global source column group.
  const int s0 = wid * 64 + lane;
  const int r0 = s0 >> 2;                       // 0..63 row within half
  const int cge = (s0 & 3) ^ ((r0 >> 1) & 3);   // swizzled col group (same both halves)

  const int arow0 = min(bm + r0, M - 1);
  const int arow1 = min(bm + r0 + 64, M - 1);

  const unsigned short* a0 = Ab + (size_t)arow0 * DDIM + cge * 8;
  const unsigned short* a1 = Ab + (size_t)arow1 * DDIM + cge * 8;
  const unsigned short* b0 = Bt + (size_t)(bn + r0) * DDIM + cge * 8;
  const unsigned short* b1 = Bt + (size_t)(bn + r0 + 64) * DDIM + cge * 8;

  unsigned short* lA0 = As + (wid * 64) * 8;    // wave-uniform bases
  unsigned short* lA1 = As + (256 + wid * 64) * 8;
  unsigned short* lB0 = Bs + (wid * 64) * 8;
  unsigned short* lB1 = Bs + (256 + wid * 64) * 8;

  const int l16 = lane & 15, lk = lane >> 4;
  const int lke = lk ^ ((l16 >> 1) & 3);        // swizzled read k-group

  for (int k0 = 0; k0 < DDIM; k0 += 32) {
    gload_lds16(a0 + k0, lA0);
    gload_lds16(a1 + k0, lA1);
    gload_lds16(b0 + k0, lB0);
    gload_lds16(b1 + k0, lB1);
    __syncthreads();

    bf16x8 af[4], bfr[4];
#pragma unroll
    for (int i = 0; i < 4; ++i) {
      af[i]  = *(const bf16x8*)&As[(wr * 64 + i * 16 + l16) * 32 + lke * 8];
      bfr[i] = *(const bf16x8*)&Bs[(wc * 64 + i * 16 + l16) * 32 + lke * 8];
    }
#pragma unroll
    for (int i = 0; i < 4; ++i)
#pragma unroll
      for (int j = 0; j < 4; ++j)
        acc[i][j] = __builtin_amdgcn_mfma_f32_16x16x32_bf16(af[i], bfr[j],
                                                            acc[i][j], 0, 0, 0);
    __syncthreads();
  }

  // Epilogue: C[row][col], col = lane&15 (+j*16), row = (lane>>4)*4+q (+i*16)
#pragma unroll
  for (int j = 0; j < 4; ++j) {
    const int col = bn + wc * 64 + j * 16 + l16;
    const float bv = bias[col];
#pragma unroll
    for (int i = 0; i < 4; ++i) {
      const int rbase = bm + wr * 64 + i * 16 + lk * 4;
#pragma unroll
      for (int qq = 0; qq < 4; ++qq) {
        const int row = rbase + qq;
        if (row < M) C[(size_t)row * DDIM + col] = f2bf(acc[i][j][qq] + bv);
      }
    }
  }
}

// ---------------------------------------------------------------------------
// CSR build: histogram of dst
// ---------------------------------------------------------------------------
__global__ __launch_bounds__(256) void hist_kernel(const int* __restrict__ dst,
                                                   int* __restrict__ deg, int E) {
  const int e = blockIdx.x * 256 + threadIdx.x;
  if (e < E) atomicAdd(&deg[dst[e]], 1);
}

// ---------------------------------------------------------------------------
// Exclusive prefix scan over deg[0..n) -> off[0..n] and cur[0..n)
// single 1024-thread block, shfl scan + wave combine.
// ---------------------------------------------------------------------------
__global__ __launch_bounds__(1024) void scan_kernel(const int* __restrict__ deg,
                                                    int* __restrict__ off,
                                                    int* __restrict__ cur, int n) {
  __shared__ int wsum[16];
  __shared__ int s_running;
  const int tid = threadIdx.x;
  const int lane = tid & 63, wid = tid >> 6;
  if (tid == 0) { s_running = 0; off[0] = 0; }
  __syncthreads();
  for (int base = 0; base < n; base += 1024) {
    const int i = base + tid;
    int v = (i < n) ? deg[i] : 0;
    int incl = v;
#pragma unroll
    for (int s = 1; s < 64; s <<= 1) {
      int t = __shfl_up(incl, s, 64);
      if (lane >= s) incl += t;
    }
    if (lane == 63) wsum[wid] = incl;
    __syncthreads();
    if (wid == 0 && lane < 16) {
      int wv = wsum[lane];
#pragma unroll
      for (int s = 1; s < 16; s <<= 1) {
        int t = __shfl_up(wv, s, 16);
        if (lane >= s) wv += t;
      }
      wsum[lane] = wv;
    }
    __syncthreads();
    const int waveoff = (wid > 0) ? wsum[wid - 1] : 0;
    const int run = s_running;
    incl += waveoff;
    if (i < n) {
      off[i + 1] = run + incl;
      cur[i] = run + incl - v;  // exclusive
    }
    __syncthreads();
    if (tid == 1023) s_running = run + incl;
    __syncthreads();
  }
}

// ---------------------------------------------------------------------------
// CSR fill: slot per edge via per-dst cursor; pack (src, weight) as uint2.
// ---------------------------------------------------------------------------
__global__ __launch_bounds__(256) void fill_kernel(
    const int* __restrict__ src, const int* __restrict__ dst,
    const float* __restrict__ ew, int* __restrict__ cur,
    uint2* __restrict__ epair, int E) {
  const int e = blockIdx.x * 256 + threadIdx.x;
  if (e >= E) return;
  const int p = atomicAdd(&cur[dst[e]], 1);
  epair[p] = make_uint2((unsigned)src[e], __float_as_uint(ew[e]));
}

// ---------------------------------------------------------------------------
// Gather: one wave per node; 2-deep edge unroll; mean + relu; single row write.
// ---------------------------------------------------------------------------
__global__ __launch_bounds__(256) void gather_kernel(
    const unsigned short* __restrict__ hp, const int* __restrict__ off,
    const uint2* __restrict__ epair, float* __restrict__ out, int n) {
  const int node = blockIdx.x * 4 + (threadIdx.x >> 6);
  if (node >= n) return;
  const int lane = threadIdx.x & 63;
  const int beg = off[node], end = off[node + 1];

  float acc[8] = {0.f, 0.f, 0.f, 0.f, 0.f, 0.f, 0.f, 0.f};
  int p = beg;
  for (; p + 2 <= end; p += 2) {
    const uint2 e0 = epair[p];
    const uint2 e1 = epair[p + 1];
    const float w0 = __uint_as_float(e0.y);
    const float w1 = __uint_as_float(e1.y);
    const uint4 u0 = *(const uint4*)(hp + (size_t)e0.x * DDIM + lane * 8);
    const uint4 u1 = *(const uint4*)(hp + (size_t)e1.x * DDIM + lane * 8);
    const unsigned a0[4] = {u0.x, u0.y, u0.z, u0.w};
    const unsigned a1[4] = {u1.x, u1.y, u1.z, u1.w};
#pragma unroll
    for (int qv = 0; qv < 4; ++qv) {
      acc[2 * qv + 0] += w0 * __uint_as_float(a0[qv] << 16) +
                         w1 * __uint_as_float(a1[qv] << 16);
      acc[2 * qv + 1] += w0 * __uint_as_float(a0[qv] & 0xffff0000u) +
                         w1 * __uint_as_float(a1[qv] & 0xffff0000u);
    }
  }
  if (p < end) {
    const uint2 e0 = epair[p];
    const float w0 = __uint_as_float(e0.y);
    const uint4 u0 = *(const uint4*)(hp + (size_t)e0.x * DDIM + lane * 8);
    const unsigned a0[4] = {u0.x, u0.y, u0.z, u0.w};
#pragma unroll
    for (int qv = 0; qv < 4; ++qv) {
      acc[2 * qv + 0] += w0 * __uint_as_float(a0[qv] << 16);
      acc[2 * qv + 1] += w0 * __uint_as_float(a0[qv] & 0xffff0000u);
    }
  }

  const float inv = 1.0f / fmaxf((float)(end - beg), 1.0f);
  float4 o0, o1;
  o0.x = fmaxf(acc[0] * inv, 0.f);
  o0.y = fmaxf(acc[1] * inv, 0.f);
  o0.z = fmaxf(acc[2] * inv, 0.f);
  o0.w = fmaxf(acc[3] * inv, 0.f);
  o1.x = fmaxf(acc[4] * inv, 0.f);
  o1.y = fmaxf(acc[5] * inv, 0.f);
  o1.z = fmaxf(acc[6] * inv, 0.f);
  o1.w = fmaxf(acc[7] * inv, 0.f);
  float* orow = out + (size_t)node * DDIM + lane * 8;
  *(float4*)(orow + 0) = o0;
  *(float4*)(orow + 4) = o1;
}

extern "C" void kernel_launch(void* const* d_in, const int* in_sizes, int n_in,
                              void* d_out, int out_size, void* d_ws, size_t ws_size,
                              hipStream_t stream) {
  const float* h  = (const float*)d_in[0];
  const float* W  = (const float*)d_in[1];
  const float* b  = (const float*)d_in[2];
  const float* ew = (const float*)d_in[3];
  const int* src  = (const int*)d_in[4];
  const int* dst  = (const int*)d_in[5];
  float* out = (float*)d_out;

  // bf16 h and Wt live in d_out (dead before gather overwrites d_out fully)
  unsigned short* hb = (unsigned short*)d_out;                                      // 51.2 MB
  unsigned short* Wt = (unsigned short*)((char*)d_out + (size_t)NNODES * DDIM * 2); // 0.5 MB

  // Workspace: hp (bf16 h_proj) + CSR arrays
  char* ws = (char*)d_ws;
  size_t o = 0;
  auto alloc = [&](size_t bytes) {
    char* p = ws + o;
    o += (bytes + 255) & ~(size_t)255;
    return p;
  };
  unsigned short* hp = (unsigned short*)alloc((size_t)NNODES * DDIM * 2);  // 51.2 MB
  int* deg    = (int*)alloc((size_t)NNODES * 4);
  int* off    = (int*)alloc((size_t)(NNODES + 1) * 4);
  int* cur    = (int*)alloc((size_t)NNODES * 4);
  uint2* epair = (uint2*)alloc((size_t)NEDGES * 8);

  // 1) fp32 -> bf16 conversions
  cvt_h_kernel<<<2048, 256, 0, stream>>>(h, hb, NNODES * DDIM / 8);
  dim3 wgrid(16, 16);
  cvt_wt_kernel<<<wgrid, 256, 0, stream>>>(W, Wt);

  // 2) MFMA GEMM: hp = bf16(hb @ Wt^T + b)
  const int mtiles = (NNODES + 127) / 128;  // 391
  gemm_mfma_kernel<<<mtiles * 4, 256, 0, stream>>>(hb, Wt, b, hp, NNODES);

  // 3) CSR build by dst
  hipMemsetAsync(deg, 0, (size_t)NNODES * 4, stream);
  hist_kernel<<<(NEDGES + 255) / 256, 256, 0, stream>>>(dst, deg, NEDGES);
  scan_kernel<<<1, 1024, 0, stream>>>(deg, off, cur, NNODES);
  fill_kernel<<<(NEDGES + 255) / 256, 256, 0, stream>>>(src, dst, ew, cur,
                                                        epair, NEDGES);

  // 4) Gather + mean + relu (one wave per node)
  gather_kernel<<<(NNODES + 3) / 4, 256, 0, stream>>>(hp, off, epair, out,
                                                      NNODES);
}

// Round 6
// 150.076 us; speedup vs baseline: 11.7524x; 1.4228x over previous
//
#include <hip/hip_runtime.h>

#define NNODES 50000
#define NEDGES 200000
#define DDIM 512

typedef __attribute__((ext_vector_type(8))) short bf16x8;
typedef __attribute__((ext_vector_type(4))) float f32x4;

static __device__ __forceinline__ unsigned short f2bf(float f) {
  unsigned u = __float_as_uint(f);
  unsigned r = (u + 0x7fffu + ((u >> 16) & 1u)) >> 16;  // RNE
  return (unsigned short)r;
}

static __device__ __forceinline__ void gload_lds16(const void* g, void* l) {
  __builtin_amdgcn_global_load_lds(
      (const __attribute__((address_space(1))) unsigned int*)g,
      (__attribute__((address_space(3))) unsigned int*)l, 16, 0, 0);
}

// ---------------------------------------------------------------------------
// Convert h (fp32) -> bf16, 8 elements/thread
// ---------------------------------------------------------------------------
__global__ __launch_bounds__(256) void cvt_h_kernel(
    const float* __restrict__ in, unsigned short* __restrict__ out, int n8) {
  for (int i = blockIdx.x * 256 + threadIdx.x; i < n8; i += gridDim.x * 256) {
    const float4 v0 = ((const float4*)in)[(size_t)i * 2];
    const float4 v1 = ((const float4*)in)[(size_t)i * 2 + 1];
    uint4 p;
    p.x = (unsigned)f2bf(v0.x) | ((unsigned)f2bf(v0.y) << 16);
    p.y = (unsigned)f2bf(v0.z) | ((unsigned)f2bf(v0.w) << 16);
    p.z = (unsigned)f2bf(v1.x) | ((unsigned)f2bf(v1.y) << 16);
    p.w = (unsigned)f2bf(v1.z) | ((unsigned)f2bf(v1.w) << 16);
    ((uint4*)out)[i] = p;
  }
}

// ---------------------------------------------------------------------------
// Wt[n][k] = bf16(W[k][n])  (512x512 transpose via LDS)
// ---------------------------------------------------------------------------
__global__ __launch_bounds__(256) void cvt_wt_kernel(
    const float* __restrict__ W, unsigned short* __restrict__ Wt) {
  __shared__ float t[32][33];
  const int n0 = blockIdx.x * 32, k0 = blockIdx.y * 32;
  const int tx = threadIdx.x & 31, ty = threadIdx.x >> 5;  // ty 0..7
  for (int r = ty; r < 32; r += 8)
    t[r][tx] = W[(size_t)(k0 + r) * DDIM + n0 + tx];
  __syncthreads();
  for (int r = ty; r < 32; r += 8)
    Wt[(size_t)(n0 + r) * DDIM + k0 + tx] = f2bf(t[tx][r]);
}

// ---------------------------------------------------------------------------
// MFMA GEMM: C_bf16[M,512] = A_bf16[M,512] @ Wt_bf16[512,512]^T + bias
// 128x128 tile, BK=32, 4 waves (2x2), 16x16x32 MFMA.
// 2-phase double-buffered LDS: STAGE(t+1) issued before COMPUTE(t); one
// vmcnt drain + barrier per K-tile (T3-minimum).
// Both-sides XOR swizzle on staging (source cg / read lk), XCD block swizzle.
// Epilogue: per-wave 64x64 C-tile staged in LDS, coalesced 16B stores
// (8 passes x 8 rows x 64 cols — FIXED from round 4's half-written tile).
// ---------------------------------------------------------------------------
__global__ __launch_bounds__(256) void gemm_mfma_kernel(
    const unsigned short* __restrict__ Ab, const unsigned short* __restrict__ Bt,
    const float* __restrict__ bias, unsigned short* __restrict__ C, int M) {
  __shared__ unsigned short As[2][128 * 32];
  __shared__ unsigned short Bs[2][128 * 32];
  const int tid = threadIdx.x;
  const int wid = tid >> 6, lane = tid & 63;

  // bijective XCD-chunked remap (8 XCDs)
  const int nwg = gridDim.x;
  const int q = nwg >> 3, rr = nwg & 7;
  const int x = blockIdx.x & 7, idx = blockIdx.x >> 3;
  const int wg = x * q + min(x, rr) + idx;

  const int mt = wg >> 2, nt = wg & 3;
  const int bm = mt * 128, bn = nt * 128;
  const int wr = wid >> 1, wc = wid & 1;

  f32x4 acc[4][4] = {};

  // staging: slot = tid; row = tid>>2 within half, swizzled col group
  const int r0 = tid >> 2;
  const int cge = (tid & 3) ^ ((r0 >> 1) & 3);

  const int arow0 = min(bm + r0, M - 1);
  const int arow1 = min(bm + r0 + 64, M - 1);

  const unsigned short* a0 = Ab + (size_t)arow0 * DDIM + cge * 8;
  const unsigned short* a1 = Ab + (size_t)arow1 * DDIM + cge * 8;
  const unsigned short* b0 = Bt + (size_t)(bn + r0) * DDIM + cge * 8;
  const unsigned short* b1 = Bt + (size_t)(bn + r0 + 64) * DDIM + cge * 8;

  const int l16 = lane & 15, lk = lane >> 4;
  const int lke = lk ^ ((l16 >> 1) & 3);  // swizzled read k-group

  // wave-uniform LDS staging bases (ushort offsets)
  const int sOff0 = (wid * 64) * 8;
  const int sOff1 = (256 + wid * 64) * 8;

#define STAGE(buf, k0)                        \
  do {                                        \
    gload_lds16(a0 + (k0), &As[buf][sOff0]);  \
    gload_lds16(a1 + (k0), &As[buf][sOff1]);  \
    gload_lds16(b0 + (k0), &Bs[buf][sOff0]);  \
    gload_lds16(b1 + (k0), &Bs[buf][sOff1]);  \
  } while (0)

#define COMPUTE(buf)                                                          \
  do {                                                                        \
    bf16x8 af[4], bfr[4];                                                     \
    _Pragma("unroll") for (int i = 0; i < 4; ++i) {                           \
      af[i]  = *(const bf16x8*)&As[buf][(wr * 64 + i * 16 + l16) * 32 + lke * 8]; \
      bfr[i] = *(const bf16x8*)&Bs[buf][(wc * 64 + i * 16 + l16) * 32 + lke * 8]; \
    }                                                                         \
    _Pragma("unroll") for (int i = 0; i < 4; ++i)                             \
        _Pragma("unroll") for (int j = 0; j < 4; ++j)                         \
            acc[i][j] = __builtin_amdgcn_mfma_f32_16x16x32_bf16(              \
                af[i], bfr[j], acc[i][j], 0, 0, 0);                           \
  } while (0)

  STAGE(0, 0);
  __syncthreads();
#pragma unroll 2
  for (int t = 0; t < 15; ++t) {
    const int cur = t & 1;
    STAGE(cur ^ 1, (t + 1) * 32);  // prefetch next tile into other buffer
    COMPUTE(cur);
    __syncthreads();               // drains vmcnt (prefetch) + lgkm
  }
  COMPUTE(1);  // tile 15 lives in buf 1
  __syncthreads();  // LDS about to be reused as epilogue scratch

  // ---- Epilogue: per-wave 64x64 bf16 tile staged in LDS, coalesced stores.
  unsigned short* cl = (wid < 2) ? &As[0][0] + wid * 4096
                                 : &Bs[0][0] + (wid - 2) * 4096;
#pragma unroll
  for (int j = 0; j < 4; ++j) {
    const float bv = bias[bn + wc * 64 + j * 16 + l16];
#pragma unroll
    for (int i = 0; i < 4; ++i)
#pragma unroll
      for (int qq = 0; qq < 4; ++qq)
        cl[(i * 16 + lk * 4 + qq) * 64 + j * 16 + l16] =
            f2bf(acc[i][j][qq] + bv);
  }
  __syncthreads();
#pragma unroll
  for (int pass = 0; pass < 8; ++pass) {
    const int rt = pass * 8 + (lane >> 3);   // row in 64x64 tile
    const int c0 = (lane & 7) * 8;           // col in 64x64 tile (8 cols/lane)
    const int grow = bm + wr * 64 + rt;
    if (grow < M) {
      const uint4 v = *(const uint4*)&cl[rt * 64 + c0];
      *(uint4*)&C[(size_t)grow * DDIM + bn + wc * 64 + c0] = v;
    }
  }
#undef STAGE
#undef COMPUTE
}

// ---------------------------------------------------------------------------
// CSR build: histogram of dst
// ---------------------------------------------------------------------------
__global__ __launch_bounds__(256) void hist_kernel(const int* __restrict__ dst,
                                                   int* __restrict__ deg, int E) {
  const int e = blockIdx.x * 256 + threadIdx.x;
  if (e < E) atomicAdd(&deg[dst[e]], 1);
}

// ---------------------------------------------------------------------------
// Parallel 3-kernel exclusive scan over deg[0..n) -> off[0..n], cur[0..n)
// ---------------------------------------------------------------------------
__global__ __launch_bounds__(256) void chunk_sum_kernel(
    const int* __restrict__ deg, int* __restrict__ part, int n) {
  const int base = blockIdx.x * 1024;
  int v = 0;
  for (int i = threadIdx.x; i < 1024; i += 256) {
    const int idx = base + i;
    v += (idx < n) ? deg[idx] : 0;
  }
#pragma unroll
  for (int s = 32; s; s >>= 1) v += __shfl_down(v, s, 64);
  __shared__ int ws[4];
  if ((threadIdx.x & 63) == 0) ws[threadIdx.x >> 6] = v;
  __syncthreads();
  if (threadIdx.x == 0) part[blockIdx.x] = ws[0] + ws[1] + ws[2] + ws[3];
}

__global__ void scan_part_kernel(int* __restrict__ part, int nb) {
  const int lane = threadIdx.x & 63;
  int v = (lane < nb) ? part[lane] : 0;
  int incl = v;
#pragma unroll
  for (int s = 1; s < 64; s <<= 1) {
    int t = __shfl_up(incl, s, 64);
    if (lane >= s) incl += t;
  }
  if (lane < nb) part[lane] = incl - v;  // exclusive
}

__global__ __launch_bounds__(1024) void chunk_scan_kernel(
    const int* __restrict__ deg, const int* __restrict__ part,
    int* __restrict__ off, int* __restrict__ cur, int n) {
  __shared__ int wsum[16];
  const int tid = threadIdx.x, lane = tid & 63, wid = tid >> 6;
  const int i = blockIdx.x * 1024 + tid;
  const int v = (i < n) ? deg[i] : 0;
  int incl = v;
#pragma unroll
  for (int s = 1; s < 64; s <<= 1) {
    int t = __shfl_up(incl, s, 64);
    if (lane >= s) incl += t;
  }
  if (lane == 63) wsum[wid] = incl;
  __syncthreads();
  if (wid == 0 && lane < 16) {
    int wv = wsum[lane];
#pragma unroll
    for (int s = 1; s < 16; s <<= 1) {
      int t = __shfl_up(wv, s, 16);
      if (lane >= s) wv += t;
    }
    wsum[lane] = wv;
  }
  __syncthreads();
  const int add = part[blockIdx.x] + ((wid > 0) ? wsum[wid - 1] : 0);
  if (i < n) {
    off[i + 1] = add + incl;
    cur[i] = add + incl - v;
  }
  if (i == 0) off[0] = 0;
}

// ---------------------------------------------------------------------------
// CSR fill: slot per edge via per-dst cursor; pack (src, weight) as uint2.
// ---------------------------------------------------------------------------
__global__ __launch_bounds__(256) void fill_kernel(
    const int* __restrict__ src, const int* __restrict__ dst,
    const float* __restrict__ ew, int* __restrict__ cur,
    uint2* __restrict__ epair, int E) {
  const int e = blockIdx.x * 256 + threadIdx.x;
  if (e >= E) return;
  const int p = atomicAdd(&cur[dst[e]], 1);
  epair[p] = make_uint2((unsigned)src[e], __float_as_uint(ew[e]));
}

// ---------------------------------------------------------------------------
// Gather: one wave per node; 2-deep edge unroll; mean + relu; single row write.
// ---------------------------------------------------------------------------
__global__ __launch_bounds__(256) void gather_kernel(
    const unsigned short* __restrict__ hp, const int* __restrict__ off,
    const uint2* __restrict__ epair, float* __restrict__ out, int n) {
  const int node = blockIdx.x * 4 + (threadIdx.x >> 6);
  if (node >= n) return;
  const int lane = threadIdx.x & 63;
  const int beg = off[node], end = off[node + 1];

  float acc[8] = {0.f, 0.f, 0.f, 0.f, 0.f, 0.f, 0.f, 0.f};
  int p = beg;
  for (; p + 2 <= end; p += 2) {
    const uint2 e0 = epair[p];
    const uint2 e1 = epair[p + 1];
    const float w0 = __uint_as_float(e0.y);
    const float w1 = __uint_as_float(e1.y);
    const uint4 u0 = *(const uint4*)(hp + (size_t)e0.x * DDIM + lane * 8);
    const uint4 u1 = *(const uint4*)(hp + (size_t)e1.x * DDIM + lane * 8);
    const unsigned a0[4] = {u0.x, u0.y, u0.z, u0.w};
    const unsigned a1[4] = {u1.x, u1.y, u1.z, u1.w};
#pragma unroll
    for (int qv = 0; qv < 4; ++qv) {
      acc[2 * qv + 0] += w0 * __uint_as_float(a0[qv] << 16) +
                         w1 * __uint_as_float(a1[qv] << 16);
      acc[2 * qv + 1] += w0 * __uint_as_float(a0[qv] & 0xffff0000u) +
                         w1 * __uint_as_float(a1[qv] & 0xffff0000u);
    }
  }
  if (p < end) {
    const uint2 e0 = epair[p];
    const float w0 = __uint_as_float(e0.y);
    const uint4 u0 = *(const uint4*)(hp + (size_t)e0.x * DDIM + lane * 8);
    const unsigned a0[4] = {u0.x, u0.y, u0.z, u0.w};
#pragma unroll
    for (int qv = 0; qv < 4; ++qv) {
      acc[2 * qv + 0] += w0 * __uint_as_float(a0[qv] << 16);
      acc[2 * qv + 1] += w0 * __uint_as_float(a0[qv] & 0xffff0000u);
    }
  }

  const float inv = 1.0f / fmaxf((float)(end - beg), 1.0f);
  float4 o0, o1;
  o0.x = fmaxf(acc[0] * inv, 0.f);
  o0.y = fmaxf(acc[1] * inv, 0.f);
  o0.z = fmaxf(acc[2] * inv, 0.f);
  o0.w = fmaxf(acc[3] * inv, 0.f);
  o1.x = fmaxf(acc[4] * inv, 0.f);
  o1.y = fmaxf(acc[5] * inv, 0.f);
  o1.z = fmaxf(acc[6] * inv, 0.f);
  o1.w = fmaxf(acc[7] * inv, 0.f);
  float* orow = out + (size_t)node * DDIM + lane * 8;
  *(float4*)(orow + 0) = o0;
  *(float4*)(orow + 4) = o1;
}

extern "C" void kernel_launch(void* const* d_in, const int* in_sizes, int n_in,
                              void* d_out, int out_size, void* d_ws, size_t ws_size,
                              hipStream_t stream) {
  const float* h  = (const float*)d_in[0];
  const float* W  = (const float*)d_in[1];
  const float* b  = (const float*)d_in[2];
  const float* ew = (const float*)d_in[3];
  const int* src  = (const int*)d_in[4];
  const int* dst  = (const int*)d_in[5];
  float* out = (float*)d_out;

  // bf16 h and Wt live in d_out (dead before gather overwrites d_out fully)
  unsigned short* hb = (unsigned short*)d_out;                                      // 51.2 MB
  unsigned short* Wt = (unsigned short*)((char*)d_out + (size_t)NNODES * DDIM * 2); // 0.5 MB

  // Workspace: hp (bf16 h_proj) + CSR arrays
  char* ws = (char*)d_ws;
  size_t o = 0;
  auto alloc = [&](size_t bytes) {
    char* p = ws + o;
    o += (bytes + 255) & ~(size_t)255;
    return p;
  };
  unsigned short* hp = (unsigned short*)alloc((size_t)NNODES * DDIM * 2);  // 51.2 MB
  int* deg    = (int*)alloc((size_t)NNODES * 4);
  int* off    = (int*)alloc((size_t)(NNODES + 1) * 4);
  int* cur    = (int*)alloc((size_t)NNODES * 4);
  uint2* epair = (uint2*)alloc((size_t)NEDGES * 8);
  int* part   = (int*)alloc(64 * 4);

  const int nchunks = (NNODES + 1023) / 1024;  // 49

  // 1) fp32 -> bf16 conversions
  cvt_h_kernel<<<2048, 256, 0, stream>>>(h, hb, NNODES * DDIM / 8);
  dim3 wgrid(16, 16);
  cvt_wt_kernel<<<wgrid, 256, 0, stream>>>(W, Wt);

  // 2) MFMA GEMM: hp = bf16(hb @ Wt^T + b)
  const int mtiles = (NNODES + 127) / 128;  // 391
  gemm_mfma_kernel<<<mtiles * 4, 256, 0, stream>>>(hb, Wt, b, hp, NNODES);

  // 3) CSR build by dst (parallel scan)
  hipMemsetAsync(deg, 0, (size_t)NNODES * 4, stream);
  hist_kernel<<<(NEDGES + 255) / 256, 256, 0, stream>>>(dst, deg, NEDGES);
  chunk_sum_kernel<<<nchunks, 256, 0, stream>>>(deg, part, NNODES);
  scan_part_kernel<<<1, 64, 0, stream>>>(part, nchunks);
  chunk_scan_kernel<<<nchunks, 1024, 0, stream>>>(deg, part, off, cur, NNODES);
  fill_kernel<<<(NEDGES + 255) / 256, 256, 0, stream>>>(src, dst, ew, cur,
                                                        epair, NEDGES);

  // 4) Gather + mean + relu (one wave per node)
  gather_kernel<<<(NNODES + 3) / 4, 256, 0, stream>>>(hp, off, epair, out,
                                                      NNODES);
}